// Round 9
// baseline (107.105 us; speedup 1.0000x reference)
//
#include <hip/hip_runtime.h>
#include <math.h>

#define G 128
#define NCELLS (G*G)            // 16384
#define RAD 20
#define NS 41
#define NTAPS (NS*NS)           // 1681
#define NB_FULL 1850.0f         // 1 + (2R+3)^2 entries in the mean
#define NTAIL 168.0f            // (2R+3)^2 - (2R+1)^2
#define NRULES 4
#define NQ 16                   // stencil-row slices
#define QROWPAD 44
#define QBLK 144                // per-block stencil scratch stride (floats, 16B-aligned)
#define NTILES 16               // 8-row tiles
#define CONV_BLOCKS (NTILES*NRULES*NQ)   // 1024
#define REP 8                   // DIAGNOSTIC: x8 in-kernel repetition of the block pipeline

// ws layout (float offsets)
#define WOFF_TAIL 0                                 // 4 floats (pad to 16)
#define WOFF_POT  16                                // 64 * NCELLS partial potentials
#define WOFF_BW   (WOFF_POT + NRULES*NQ*NCELLS)     // 1024 * 144 per-block stencil slices

__device__ __forceinline__ float kw(float d, float irk,
                                    float rk0, float rk1, float rk2,
                                    float b0, float b1, float b2,
                                    float iw0, float iw1, float iw2) {
    float em = 1.f / (1.f + __expf((d - 1.f) * 10.f));
    float dd = d * irk;
    float u0 = (dd - rk0) * iw0;
    float u1 = (dd - rk1) * iw1;
    float u2 = (dd - rk2) * iw2;
    return em * (b0 * __expf(-0.5f * u0 * u0)
               + b1 * __expf(-0.5f * u1 * u1)
               + b2 * __expf(-0.5f * u2 * u2));
}

// taps t=4q..4q+3 (stencil chunk rq) against window chunks wq, wq1.
#define CROW(rq, wq, wq1)                                                         \
    a0 = fmaf(rq.x, wq.x,  a0); a1 = fmaf(rq.x, wq.y,  a1);                       \
    a2 = fmaf(rq.x, wq.z,  a2); a3 = fmaf(rq.x, wq.w,  a3);                       \
    a0 = fmaf(rq.y, wq.y,  a0); a1 = fmaf(rq.y, wq.z,  a1);                       \
    a2 = fmaf(rq.y, wq.w,  a2); a3 = fmaf(rq.y, wq1.x, a3);                       \
    a0 = fmaf(rq.z, wq.z,  a0); a1 = fmaf(rq.z, wq.w,  a1);                       \
    a2 = fmaf(rq.z, wq1.x, a2); a3 = fmaf(rq.z, wq1.y, a3);                       \
    a0 = fmaf(rq.w, wq.w,  a0); a1 = fmaf(rq.w, wq1.x, a1);                       \
    a2 = fmaf(rq.w, wq1.y, a2); a3 = fmaf(rq.w, wq1.z, a3);

// 1024 blocks: (16 eight-row tiles) x (4 rules) x (16 stencil-row slices).
// DIAGNOSTIC build: entire per-block pipeline repeated REP times (idempotent).
__global__ __launch_bounds__(256, 4)
void lenia_conv(const float* __restrict__ x,
                const int* __restrict__ c0v,
                const float* __restrict__ rr,
                const float* __restrict__ rkv,
                const float* __restrict__ bv,
                const float* __restrict__ wv,
                float* __restrict__ ws) {
    __shared__ __align__(16) float xt[10*168];   // <= 10 halo'd rows
    __shared__ float red[4];

    const int bid  = blockIdx.x;
    const int q    = bid & 15;
    const int k    = (bid >> 4) & 3;
    const int tile = bid >> 6;                   // 0..15
    const int i0   = tile * 8;
    const int t    = threadIdx.x;
    const int nsi  = (q < 9) ? 3 : 2;
    const int si0  = (q < 9) ? 3*q : 27 + 2*(q - 9);
    const int r0   = i0 - RAD + si0;
    const int NR   = nsi + 7;                    // staged rows (<=10)
    const int ck   = c0v[k];                     // wave-uniform

    #pragma unroll 1
    for (int rep = 0; rep < REP; ++rep) {
        asm volatile("" ::: "memory");           // force re-execution of loads/stores

        // ---- stage halo'd channel tile straight from interleaved x ----
        for (int idx = t; idx < NR * 168; idx += 256) {
            int rrow = idx / 168;
            int cc   = idx - rrow * 168;
            int grow = (r0 + rrow) & (G - 1);
            int gcol = (cc - 20) & (G - 1);
            xt[rrow*168 + cc] = x[grow*(G*3) + gcol*3 + ck];
        }

        // ---- per-block stencil recompute ----
        const float irk = 1.f / rr[k];
        const float rk0 = rkv[k*3+0], rk1 = rkv[k*3+1], rk2 = rkv[k*3+2];
        const float b0  = bv[k*3+0],  b1  = bv[k*3+1],  b2  = bv[k*3+2];
        const float iw0 = 1.f / wv[k*3+0], iw1 = 1.f / wv[k*3+1], iw2 = 1.f / wv[k*3+2];
        const float invR = 1.f / (float)RAD;

        float vals[7];
        float lsum = 0.f;
        #pragma unroll
        for (int j = 0; j < 7; ++j) {
            int sidx = t + j * 256;
            float wk = 0.f;
            if (sidx < NTAPS) {
                int si = sidx / NS - RAD;
                int sj = sidx % NS - RAD;
                float d = sqrtf((float)(si*si + sj*sj)) * invR;
                wk = kw(d, irk, rk0, rk1, rk2, b0, b1, b2, iw0, iw1, iw2);
            }
            vals[j] = wk;
            lsum += wk;
        }
        #pragma unroll
        for (int mm = 32; mm > 0; mm >>= 1) lsum += __shfl_xor(lsum, mm, 64);
        if ((t & 63) == 0) red[t >> 6] = lsum;
        __syncthreads();                          // red ready AND xt staged
        const float S4 = red[0] + red[1] + red[2] + red[3];
        const float wself = kw(0.f, irk, rk0, rk1, rk2, b0, b1, b2, iw0, iw1, iw2);
        const float dtail = sqrtf(8192.f) * invR;
        const float wtail = kw(dtail, irk, rk0, rk1, rk2, b0, b1, b2, iw0, iw1, iw2);
        const float S = S4 + wself + NTAIL * wtail;
        const float inv = 1.f / (S * NB_FULL);

        float* bw = ws + WOFF_BW + bid * QBLK;
        const int lo = si0 * NS, hi = (si0 + nsi) * NS;
        #pragma unroll
        for (int j = 0; j < 7; ++j) {
            int sidx = t + j * 256;
            if (sidx >= lo && sidx < hi) {
                float v = vals[j] * inv;
                if (sidx == RAD*NS + RAD) v += wself * inv;
                int l = sidx - lo;
                bw[(l / NS) * QROWPAD + (l % NS)] = v;
            }
        }
        if (t < 9) bw[(t / 3) * QROWPAD + NS + (t % 3)] = 0.f;
        if (tile == 0 && q == 0 && t == 0) ws[WOFF_TAIL + k] = NTAIL * wtail * inv;
        __syncthreads();                          // bw visible block-wide

        // ---- conv: 8 rows x 32 lanes, 4 adjacent cells per thread ----
        const int row = t >> 5;
        const int cb  = (t & 31) * 4;
        float a0 = 0.f, a1 = 0.f, a2 = 0.f, a3 = 0.f;

        #pragma unroll
        for (int ii = 0; ii < 3; ++ii) {
            if (ii < nsi) {
                const float4* wp  = (const float4*)&xt[(row + ii)*168 + cb];
                const float4* rp4 = (const float4*)(bw + ii * QROWPAD);
                float4 w0 = wp[0], w1 = wp[1], w2 = wp[2], w3 = wp[3], w4 = wp[4], w5 = wp[5];
                float4 w6 = wp[6], w7 = wp[7], w8 = wp[8], w9 = wp[9], w10 = wp[10];
                float4 r0v = rp4[0], r1 = rp4[1], r2 = rp4[2], r3 = rp4[3], r4 = rp4[4], r5 = rp4[5];
                float4 r6 = rp4[6], r7 = rp4[7], r8 = rp4[8], r9 = rp4[9], r10 = rp4[10];
                CROW(r0v, w0, w1)  CROW(r1, w1, w2)  CROW(r2, w2, w3)  CROW(r3, w3, w4)
                CROW(r4, w4, w5)  CROW(r5, w5, w6)  CROW(r6, w6, w7)  CROW(r7, w7, w8)
                CROW(r8, w8, w9)  CROW(r9, w9, w10)
                a0 = fmaf(r10.x, w10.x, a0);
                a1 = fmaf(r10.x, w10.y, a1);
                a2 = fmaf(r10.x, w10.z, a2);
                a3 = fmaf(r10.x, w10.w, a3);
            }
        }

        int cell = (i0 + row) * G + cb;
        float4 res; res.x = a0; res.y = a1; res.z = a2; res.w = a3;
        *(float4*)&ws[WOFF_POT + (k * NQ + q) * NCELLS + cell] = res;

        __syncthreads();                          // protect xt/red across reps
    }
}

// 128 blocks x 128 threads: sum 64 partials, growth, delta, clip, pos pass-through.
__global__ __launch_bounds__(128)
void lenia_update(const float* __restrict__ pos,
                  const float* __restrict__ x,
                  const int* __restrict__ c0v,
                  const int* __restrict__ c1v,
                  const float* __restrict__ hv,
                  const float* __restrict__ mv,
                  const float* __restrict__ sv,
                  const float* __restrict__ ws,
                  float* __restrict__ out) {
    int n = blockIdx.x * 128 + threadIdx.x;
    *(float2*)&out[2*n] = *(const float2*)&pos[2*n];

    float xv0 = x[n*3 + 0], xv1 = x[n*3 + 1], xv2 = x[n*3 + 2];
    float d0 = 0.f, d1 = 0.f, d2 = 0.f;
    #pragma unroll
    for (int kk = 0; kk < NRULES; ++kk) {
        float pot = ws[WOFF_TAIL + kk] * x[c0v[kk]];
        #pragma unroll
        for (int qq = 0; qq < NQ; ++qq)
            pot += ws[WOFF_POT + (kk * NQ + qq) * NCELLS + n];
        float u = pot - mv[kk];
        float sk = sv[kk];
        float field = __expf(-u*u / (2.f * sk * sk) - 0.001f) * 2.f - 1.f;
        float add = hv[kk] * field;
        int c = c1v[kk];
        if (c == 0) d0 += add; else if (c == 1) d1 += add; else d2 += add;
    }
    float* ox = out + 2 * NCELLS;
    ox[n*3 + 0] = fminf(fmaxf(xv0 + d0 * 0.1f, 0.f), 1.f);
    ox[n*3 + 1] = fminf(fmaxf(xv1 + d1 * 0.1f, 0.f), 1.f);
    ox[n*3 + 2] = fminf(fmaxf(xv2 + d2 * 0.1f, 0.f), 1.f);
}

extern "C" void kernel_launch(void* const* d_in, const int* in_sizes, int n_in,
                              void* d_out, int out_size, void* d_ws, size_t ws_size,
                              hipStream_t stream) {
    const float* pos = (const float*)d_in[0];
    const float* x   = (const float*)d_in[1];
    const int*   c0  = (const int*)  d_in[2];
    const int*   c1  = (const int*)  d_in[3];
    const float* r   = (const float*)d_in[4];
    const float* rk  = (const float*)d_in[5];
    const float* b   = (const float*)d_in[6];
    const float* w   = (const float*)d_in[7];
    const float* h   = (const float*)d_in[8];
    const float* m   = (const float*)d_in[9];
    const float* s   = (const float*)d_in[10];
    float* out = (float*)d_out;
    float* ws  = (float*)d_ws;

    lenia_conv<<<CONV_BLOCKS, 256, 0, stream>>>(x, c0, r, rk, b, w, ws);
    lenia_update<<<NCELLS/128, 128, 0, stream>>>(pos, x, c0, c1, h, m, s, ws, out);
}

// Round 10
// 26.484 us; speedup vs baseline: 4.0441x; 4.0441x over previous
//
#include <hip/hip_runtime.h>
#include <math.h>

#define G 128
#define NCELLS (G*G)            // 16384
#define RAD 20
#define NS 41
#define NTAPS (NS*NS)           // 1681
#define NB_FULL 1850.0f         // 1 + (2R+3)^2 entries in the mean
#define NTAIL 168.0f            // (2R+3)^2 - (2R+1)^2
#define NRULES 4
#define NQ 16                   // stencil-row slices
#define SROWPAD 44              // stencil row stride (41 + 3 zero pad)
#define SSZ (NS*SROWPAD)        // 1804 floats per rule
#define NTILES 16               // 8-row tiles
#define CONV_BLOCKS (NTILES*NRULES*NQ)   // 1024

// ws layout (float offsets)
#define WOFF_TAIL 0                                 // 4 floats (pad to 16)
#define WOFF_STEN 16                                // [4][41][44] normalized stencils
#define WOFF_POT  (WOFF_STEN + NRULES*SSZ)          // 7232: 64 * NCELLS partial potentials

__device__ __forceinline__ float kw(float d, float irk,
                                    float rk0, float rk1, float rk2,
                                    float b0, float b1, float b2,
                                    float iw0, float iw1, float iw2) {
    float em = 1.f / (1.f + __expf((d - 1.f) * 10.f));
    float dd = d * irk;
    float u0 = (dd - rk0) * iw0;
    float u1 = (dd - rk1) * iw1;
    float u2 = (dd - rk2) * iw2;
    return em * (b0 * __expf(-0.5f * u0 * u0)
               + b1 * __expf(-0.5f * u1 * u1)
               + b2 * __expf(-0.5f * u2 * u2));
}

// 4 blocks: block k computes rule k's normalized [41][44] stencil + tail scalar.
__global__ __launch_bounds__(256)
void lenia_prep(const float* __restrict__ rr,
                const float* __restrict__ rkv,
                const float* __restrict__ bv,
                const float* __restrict__ wv,
                float* __restrict__ ws) {
    __shared__ float red[4];
    const int k = blockIdx.x;
    const int t = threadIdx.x;

    const float irk = 1.f / rr[k];
    const float rk0 = rkv[k*3+0], rk1 = rkv[k*3+1], rk2 = rkv[k*3+2];
    const float b0  = bv[k*3+0],  b1  = bv[k*3+1],  b2  = bv[k*3+2];
    const float iw0 = 1.f / wv[k*3+0], iw1 = 1.f / wv[k*3+1], iw2 = 1.f / wv[k*3+2];
    const float invR = 1.f / (float)RAD;

    float vals[7];
    float lsum = 0.f;
    #pragma unroll
    for (int j = 0; j < 7; ++j) {
        int sidx = t + j * 256;
        float wk = 0.f;
        if (sidx < NTAPS) {
            int si = sidx / NS - RAD;
            int sj = sidx % NS - RAD;
            float d = sqrtf((float)(si*si + sj*sj)) * invR;
            wk = kw(d, irk, rk0, rk1, rk2, b0, b1, b2, iw0, iw1, iw2);
        }
        vals[j] = wk;
        lsum += wk;
    }
    #pragma unroll
    for (int mm = 32; mm > 0; mm >>= 1) lsum += __shfl_xor(lsum, mm, 64);
    if ((t & 63) == 0) red[t >> 6] = lsum;
    __syncthreads();
    const float S4 = red[0] + red[1] + red[2] + red[3];
    const float wself = kw(0.f, irk, rk0, rk1, rk2, b0, b1, b2, iw0, iw1, iw2);
    const float dtail = sqrtf(8192.f) * invR;
    const float wtail = kw(dtail, irk, rk0, rk1, rk2, b0, b1, b2, iw0, iw1, iw2);
    const float S = S4 + wself + NTAIL * wtail;
    const float inv = 1.f / (S * NB_FULL);

    float* st = ws + WOFF_STEN + k * SSZ;
    #pragma unroll
    for (int j = 0; j < 7; ++j) {
        int sidx = t + j * 256;
        if (sidx < NTAPS) {
            float v = vals[j] * inv;
            if (sidx == RAD*NS + RAD) v += wself * inv;   // fold self slot into (0,0)
            st[(sidx / NS) * SROWPAD + (sidx % NS)] = v;
        }
    }
    for (int j = t; j < NS * 3; j += 256)                 // zero the 3 pad cols
        st[(j / 3) * SROWPAD + NS + (j % 3)] = 0.f;
    if (t == 0) ws[WOFF_TAIL + k] = NTAIL * wtail * inv;
}

// taps t=4q..4q+3 (stencil chunk rq) against window chunks wq, wq1.
// Ascending-tap FMA order per accumulator (matches prior rounds).
#define CROW(rq, wq, wq1)                                                         \
    a0 = fmaf(rq.x, wq.x,  a0); a1 = fmaf(rq.x, wq.y,  a1);                       \
    a2 = fmaf(rq.x, wq.z,  a2); a3 = fmaf(rq.x, wq.w,  a3);                       \
    a0 = fmaf(rq.y, wq.y,  a0); a1 = fmaf(rq.y, wq.z,  a1);                       \
    a2 = fmaf(rq.y, wq.w,  a2); a3 = fmaf(rq.y, wq1.x, a3);                       \
    a0 = fmaf(rq.z, wq.z,  a0); a1 = fmaf(rq.z, wq.w,  a1);                       \
    a2 = fmaf(rq.z, wq1.x, a2); a3 = fmaf(rq.z, wq1.y, a3);                       \
    a0 = fmaf(rq.w, wq.w,  a0); a1 = fmaf(rq.w, wq1.x, a1);                       \
    a2 = fmaf(rq.w, wq1.y, a2); a3 = fmaf(rq.w, wq1.z, a3);

// 1024 blocks: (16 eight-row tiles) x (4 rules) x (16 stencil-row slices).
// 256 threads = 8 rows x 32 lanes; 4 adjacent cells per thread.
// Stencil slice staged to LDS (528 B); reads are same-address broadcasts.
__global__ __launch_bounds__(256, 4)
void lenia_conv(const float* __restrict__ x,
                const int* __restrict__ c0v,
                float* __restrict__ ws) {
    __shared__ __align__(16) float sten[3*SROWPAD];   // <= 3 stencil rows
    __shared__ __align__(16) float xt[10*168];        // <= 10 halo'd rows

    const int bid  = blockIdx.x;
    const int q    = bid & 15;
    const int k    = (bid >> 4) & 3;
    const int tile = bid >> 6;                   // 0..15
    const int i0   = tile * 8;
    const int t    = threadIdx.x;
    // slices: nine rows-of-3 then seven rows-of-2 (9*3 + 7*2 = 41)
    const int nsi  = (q < 9) ? 3 : 2;
    const int si0  = (q < 9) ? 3*q : 27 + 2*(q - 9);
    const int r0   = i0 - RAD + si0;
    const int NR   = nsi + 7;                    // staged rows (<=10)
    const int ck   = c0v[k];                     // wave-uniform

    // ---- stage stencil slice (coalesced, 88-132 floats) ----
    if (t < nsi * SROWPAD)
        sten[t] = ws[WOFF_STEN + k * SSZ + si0 * SROWPAD + t];

    // ---- stage halo'd channel tile straight from interleaved x ----
    for (int idx = t; idx < NR * 168; idx += 256) {
        int rrow = idx / 168;
        int cc   = idx - rrow * 168;
        int grow = (r0 + rrow) & (G - 1);
        int gcol = (cc - 20) & (G - 1);
        xt[rrow*168 + cc] = x[grow*(G*3) + gcol*3 + ck];
    }
    __syncthreads();

    // ---- conv: 8 rows x 32 lanes, 4 adjacent cells per thread ----
    const int row = t >> 5;
    const int cb  = (t & 31) * 4;
    float a0 = 0.f, a1 = 0.f, a2 = 0.f, a3 = 0.f;

    #pragma unroll
    for (int ii = 0; ii < 3; ++ii) {
        if (ii < nsi) {
            const float4* wp  = (const float4*)&xt[(row + ii)*168 + cb];  // per-lane
            const float4* rp4 = (const float4*)&sten[ii * SROWPAD];       // broadcast
            float4 w0 = wp[0], w1 = wp[1], w2 = wp[2], w3 = wp[3], w4 = wp[4], w5 = wp[5];
            float4 w6 = wp[6], w7 = wp[7], w8 = wp[8], w9 = wp[9], w10 = wp[10];
            float4 r0v = rp4[0], r1 = rp4[1], r2 = rp4[2], r3 = rp4[3], r4 = rp4[4], r5 = rp4[5];
            float4 r6 = rp4[6], r7 = rp4[7], r8 = rp4[8], r9 = rp4[9], r10 = rp4[10];
            CROW(r0v, w0, w1)  CROW(r1, w1, w2)  CROW(r2, w2, w3)  CROW(r3, w3, w4)
            CROW(r4, w4, w5)  CROW(r5, w5, w6)  CROW(r6, w6, w7)  CROW(r7, w7, w8)
            CROW(r8, w8, w9)  CROW(r9, w9, w10)
            a0 = fmaf(r10.x, w10.x, a0);                  // tap 40 (41..43 are zero)
            a1 = fmaf(r10.x, w10.y, a1);
            a2 = fmaf(r10.x, w10.z, a2);
            a3 = fmaf(r10.x, w10.w, a3);
        }
    }

    int cell = (i0 + row) * G + cb;
    float4 res; res.x = a0; res.y = a1; res.z = a2; res.w = a3;
    *(float4*)&ws[WOFF_POT + (k * NQ + q) * NCELLS + cell] = res;
}

// 128 blocks x 128 threads: sum 64 partials, growth, delta, clip, pos pass-through.
__global__ __launch_bounds__(128)
void lenia_update(const float* __restrict__ pos,
                  const float* __restrict__ x,
                  const int* __restrict__ c0v,
                  const int* __restrict__ c1v,
                  const float* __restrict__ hv,
                  const float* __restrict__ mv,
                  const float* __restrict__ sv,
                  const float* __restrict__ ws,
                  float* __restrict__ out) {
    int n = blockIdx.x * 128 + threadIdx.x;
    *(float2*)&out[2*n] = *(const float2*)&pos[2*n];

    float xv0 = x[n*3 + 0], xv1 = x[n*3 + 1], xv2 = x[n*3 + 2];
    float d0 = 0.f, d1 = 0.f, d2 = 0.f;
    #pragma unroll
    for (int kk = 0; kk < NRULES; ++kk) {
        float pot = ws[WOFF_TAIL + kk] * x[c0v[kk]];   // tail slots all index cell 0
        #pragma unroll
        for (int qq = 0; qq < NQ; ++qq)
            pot += ws[WOFF_POT + (kk * NQ + qq) * NCELLS + n];
        float u = pot - mv[kk];
        float sk = sv[kk];
        float field = __expf(-u*u / (2.f * sk * sk) - 0.001f) * 2.f - 1.f;
        float add = hv[kk] * field;
        int c = c1v[kk];   // wave-uniform
        if (c == 0) d0 += add; else if (c == 1) d1 += add; else d2 += add;
    }
    float* ox = out + 2 * NCELLS;
    ox[n*3 + 0] = fminf(fmaxf(xv0 + d0 * 0.1f, 0.f), 1.f);
    ox[n*3 + 1] = fminf(fmaxf(xv1 + d1 * 0.1f, 0.f), 1.f);
    ox[n*3 + 2] = fminf(fmaxf(xv2 + d2 * 0.1f, 0.f), 1.f);
}

extern "C" void kernel_launch(void* const* d_in, const int* in_sizes, int n_in,
                              void* d_out, int out_size, void* d_ws, size_t ws_size,
                              hipStream_t stream) {
    const float* pos = (const float*)d_in[0];
    const float* x   = (const float*)d_in[1];
    const int*   c0  = (const int*)  d_in[2];
    const int*   c1  = (const int*)  d_in[3];
    const float* r   = (const float*)d_in[4];
    const float* rk  = (const float*)d_in[5];
    const float* b   = (const float*)d_in[6];
    const float* w   = (const float*)d_in[7];
    const float* h   = (const float*)d_in[8];
    const float* m   = (const float*)d_in[9];
    const float* s   = (const float*)d_in[10];
    float* out = (float*)d_out;
    float* ws  = (float*)d_ws;

    lenia_prep<<<NRULES, 256, 0, stream>>>(r, rk, b, w, ws);
    lenia_conv<<<CONV_BLOCKS, 256, 0, stream>>>(x, c0, ws);
    lenia_update<<<NCELLS/128, 128, 0, stream>>>(pos, x, c0, c1, h, m, s, ws, out);
}

// Round 11
// 25.574 us; speedup vs baseline: 4.1880x; 1.0356x over previous
//
#include <hip/hip_runtime.h>
#include <math.h>

#define G 128
#define NCELLS (G*G)            // 16384
#define RAD 20
#define NS 41
#define NTAPS (NS*NS)           // 1681
#define NB_FULL 1850.0f         // 1 + (2R+3)^2 entries in the mean
#define NTAIL 168.0f            // (2R+3)^2 - (2R+1)^2
#define NRULES 4
#define NQ 16                   // stencil-row slices
#define SROWPAD 44              // stencil row stride (41 + 3 zero pad)
#define SSZ (NS*SROWPAD)        // 1804 floats per rule
#define NTILES 16               // 8-row tiles
#define CONV_BLOCKS (NTILES*NRULES*NQ)   // 1024

// ws layout (float offsets)
#define WOFF_TAIL  0                                // 4 floats (pad to 16)
#define WOFF_STEN  16                               // [4][41][44] normalized stencils
#define WOFF_POT   (WOFF_STEN + NRULES*SSZ)         // 7232: 64 * NCELLS partial potentials
#define WOFF_PLANE (WOFF_POT + NRULES*NQ*NCELLS)    // 3 * NCELLS planar channels

__device__ __forceinline__ float kw(float d, float irk,
                                    float rk0, float rk1, float rk2,
                                    float b0, float b1, float b2,
                                    float iw0, float iw1, float iw2) {
    float em = 1.f / (1.f + __expf((d - 1.f) * 10.f));
    float dd = d * irk;
    float u0 = (dd - rk0) * iw0;
    float u1 = (dd - rk1) * iw1;
    float u2 = (dd - rk2) * iw2;
    return em * (b0 * __expf(-0.5f * u0 * u0)
               + b1 * __expf(-0.5f * u1 * u1)
               + b2 * __expf(-0.5f * u2 * u2));
}

// blocks 0..3: rule-k stencil. blocks 4..67: deinterleave x -> 3 planar planes.
__global__ __launch_bounds__(256)
void lenia_prep(const float* __restrict__ x,
                const float* __restrict__ rr,
                const float* __restrict__ rkv,
                const float* __restrict__ bv,
                const float* __restrict__ wv,
                float* __restrict__ ws) {
    const int bid = blockIdx.x;
    const int t = threadIdx.x;

    if (bid >= NRULES) {
        int n = (bid - NRULES) * 256 + t;
        float v0 = x[n*3 + 0];
        float v1 = x[n*3 + 1];
        float v2 = x[n*3 + 2];
        ws[WOFF_PLANE + 0*NCELLS + n] = v0;
        ws[WOFF_PLANE + 1*NCELLS + n] = v1;
        ws[WOFF_PLANE + 2*NCELLS + n] = v2;
        return;
    }

    __shared__ float red[4];
    const int k = bid;
    const float irk = 1.f / rr[k];
    const float rk0 = rkv[k*3+0], rk1 = rkv[k*3+1], rk2 = rkv[k*3+2];
    const float b0  = bv[k*3+0],  b1  = bv[k*3+1],  b2  = bv[k*3+2];
    const float iw0 = 1.f / wv[k*3+0], iw1 = 1.f / wv[k*3+1], iw2 = 1.f / wv[k*3+2];
    const float invR = 1.f / (float)RAD;

    float vals[7];
    float lsum = 0.f;
    #pragma unroll
    for (int j = 0; j < 7; ++j) {
        int sidx = t + j * 256;
        float wk = 0.f;
        if (sidx < NTAPS) {
            int si = sidx / NS - RAD;
            int sj = sidx % NS - RAD;
            float d = sqrtf((float)(si*si + sj*sj)) * invR;
            wk = kw(d, irk, rk0, rk1, rk2, b0, b1, b2, iw0, iw1, iw2);
        }
        vals[j] = wk;
        lsum += wk;
    }
    #pragma unroll
    for (int mm = 32; mm > 0; mm >>= 1) lsum += __shfl_xor(lsum, mm, 64);
    if ((t & 63) == 0) red[t >> 6] = lsum;
    __syncthreads();
    const float S4 = red[0] + red[1] + red[2] + red[3];
    const float wself = kw(0.f, irk, rk0, rk1, rk2, b0, b1, b2, iw0, iw1, iw2);
    const float dtail = sqrtf(8192.f) * invR;
    const float wtail = kw(dtail, irk, rk0, rk1, rk2, b0, b1, b2, iw0, iw1, iw2);
    const float S = S4 + wself + NTAIL * wtail;
    const float inv = 1.f / (S * NB_FULL);

    float* st = ws + WOFF_STEN + k * SSZ;
    #pragma unroll
    for (int j = 0; j < 7; ++j) {
        int sidx = t + j * 256;
        if (sidx < NTAPS) {
            float v = vals[j] * inv;
            if (sidx == RAD*NS + RAD) v += wself * inv;   // fold self slot into (0,0)
            st[(sidx / NS) * SROWPAD + (sidx % NS)] = v;
        }
    }
    for (int j = t; j < NS * 3; j += 256)                 // zero the 3 pad cols
        st[(j / 3) * SROWPAD + NS + (j % 3)] = 0.f;
    if (t == 0) ws[WOFF_TAIL + k] = NTAIL * wtail * inv;
}

// taps t=4q..4q+3 (stencil chunk rq) against window chunks wq, wq1.
#define CROW(rq, wq, wq1)                                                         \
    a0 = fmaf(rq.x, wq.x,  a0); a1 = fmaf(rq.x, wq.y,  a1);                       \
    a2 = fmaf(rq.x, wq.z,  a2); a3 = fmaf(rq.x, wq.w,  a3);                       \
    a0 = fmaf(rq.y, wq.y,  a0); a1 = fmaf(rq.y, wq.z,  a1);                       \
    a2 = fmaf(rq.y, wq.w,  a2); a3 = fmaf(rq.y, wq1.x, a3);                       \
    a0 = fmaf(rq.z, wq.z,  a0); a1 = fmaf(rq.z, wq.w,  a1);                       \
    a2 = fmaf(rq.z, wq1.x, a2); a3 = fmaf(rq.z, wq1.y, a3);                       \
    a0 = fmaf(rq.w, wq.w,  a0); a1 = fmaf(rq.w, wq1.x, a1);                       \
    a2 = fmaf(rq.w, wq1.y, a2); a3 = fmaf(rq.w, wq1.z, a3);

// 1024 blocks: (16 eight-row tiles) x (4 rules) x (16 stencil-row slices).
// 256 threads = 8 rows x 32 lanes; 4 adjacent cells per thread.
// Staging now division-free + fully coalesced float4 from the planar plane.
__global__ __launch_bounds__(256, 4)
void lenia_conv(const int* __restrict__ c0v, float* __restrict__ ws) {
    __shared__ __align__(16) float sten[3*SROWPAD];   // <= 3 stencil rows
    __shared__ __align__(16) float xt[10*168];        // <= 10 halo'd rows ([10][42] f4)

    const int bid  = blockIdx.x;
    const int q    = bid & 15;
    const int k    = (bid >> 4) & 3;
    const int tile = bid >> 6;                   // 0..15
    const int i0   = tile * 8;
    const int t    = threadIdx.x;
    // slices: nine rows-of-3 then seven rows-of-2 (9*3 + 7*2 = 41)
    const int nsi  = (q < 9) ? 3 : 2;
    const int si0  = (q < 9) ? 3*q : 27 + 2*(q - 9);
    const int r0   = i0 - RAD + si0;
    const int NR   = nsi + 7;                    // staged rows (9 or 10)
    const int ck   = c0v[k];                     // wave-uniform

    const float4* xp4 = (const float4*)(ws + WOFF_PLANE + ck * NCELLS);  // [128][32] f4
    float4* xt4 = (float4*)xt;                   // [NR][42] f4

    // ---- stage stencil slice (coalesced f4) ----
    if (t < nsi * 11)
        ((float4*)sten)[t] = ((const float4*)(ws + WOFF_STEN + k * SSZ))[si0 * 11 + t];

    // ---- stage interior: rows 0..7 (and 8..NR-1), f4-coalesced, no divisions ----
    {
        int row = t >> 5, lane = t & 31;
        int grow = (r0 + row) & (G - 1);
        xt4[row * 42 + 5 + lane] = xp4[grow * 32 + lane];
        if (t < (NR - 8) * 32) {
            row = 8 + (t >> 5);
            grow = (r0 + row) & (G - 1);
            xt4[row * 42 + 5 + lane] = xp4[grow * 32 + lane];
        }
    }
    // ---- stage wrap halo: 16 lanes per row, 10 f4 per row ----
    if (t < NR * 16) {
        int row = t >> 4, slot = t & 15;
        int grow = (r0 + row) & (G - 1);
        if (slot < 5)        xt4[row * 42 + slot]        = xp4[grow * 32 + 27 + slot];
        else if (slot < 10)  xt4[row * 42 + 32 + slot]   = xp4[grow * 32 + slot - 5];
    }
    __syncthreads();

    // ---- conv: 8 rows x 32 lanes, 4 adjacent cells per thread ----
    const int row = t >> 5;
    const int cb  = (t & 31) * 4;
    float a0 = 0.f, a1 = 0.f, a2 = 0.f, a3 = 0.f;

    #pragma unroll
    for (int ii = 0; ii < 3; ++ii) {
        if (ii < nsi) {
            const float4* wp  = (const float4*)&xt[(row + ii)*168 + cb];  // per-lane
            const float4* rp4 = (const float4*)&sten[ii * SROWPAD];       // broadcast
            float4 w0 = wp[0], w1 = wp[1], w2 = wp[2], w3 = wp[3], w4 = wp[4], w5 = wp[5];
            float4 w6 = wp[6], w7 = wp[7], w8 = wp[8], w9 = wp[9], w10 = wp[10];
            float4 r0v = rp4[0], r1 = rp4[1], r2 = rp4[2], r3 = rp4[3], r4 = rp4[4], r5 = rp4[5];
            float4 r6 = rp4[6], r7 = rp4[7], r8 = rp4[8], r9 = rp4[9], r10 = rp4[10];
            CROW(r0v, w0, w1)  CROW(r1, w1, w2)  CROW(r2, w2, w3)  CROW(r3, w3, w4)
            CROW(r4, w4, w5)  CROW(r5, w5, w6)  CROW(r6, w6, w7)  CROW(r7, w7, w8)
            CROW(r8, w8, w9)  CROW(r9, w9, w10)
            a0 = fmaf(r10.x, w10.x, a0);                  // tap 40 (41..43 are zero)
            a1 = fmaf(r10.x, w10.y, a1);
            a2 = fmaf(r10.x, w10.z, a2);
            a3 = fmaf(r10.x, w10.w, a3);
        }
    }

    int cell = (i0 + row) * G + cb;
    float4 res; res.x = a0; res.y = a1; res.z = a2; res.w = a3;
    *(float4*)&ws[WOFF_POT + (k * NQ + q) * NCELLS + cell] = res;
}

// 256 blocks x 64 threads (1 wave on every CU): sum partials, growth, clip, pos copy.
__global__ __launch_bounds__(64)
void lenia_update(const float* __restrict__ pos,
                  const float* __restrict__ x,
                  const int* __restrict__ c0v,
                  const int* __restrict__ c1v,
                  const float* __restrict__ hv,
                  const float* __restrict__ mv,
                  const float* __restrict__ sv,
                  const float* __restrict__ ws,
                  float* __restrict__ out) {
    int n = blockIdx.x * 64 + threadIdx.x;
    *(float2*)&out[2*n] = *(const float2*)&pos[2*n];

    float xv0 = x[n*3 + 0], xv1 = x[n*3 + 1], xv2 = x[n*3 + 2];
    float d0 = 0.f, d1 = 0.f, d2 = 0.f;
    #pragma unroll
    for (int kk = 0; kk < NRULES; ++kk) {
        float pot = ws[WOFF_TAIL + kk] * x[c0v[kk]];   // tail slots all index cell 0
        #pragma unroll
        for (int qq = 0; qq < NQ; ++qq)
            pot += ws[WOFF_POT + (kk * NQ + qq) * NCELLS + n];
        float u = pot - mv[kk];
        float sk = sv[kk];
        float field = __expf(-u*u / (2.f * sk * sk) - 0.001f) * 2.f - 1.f;
        float add = hv[kk] * field;
        int c = c1v[kk];   // wave-uniform
        if (c == 0) d0 += add; else if (c == 1) d1 += add; else d2 += add;
    }
    float* ox = out + 2 * NCELLS;
    ox[n*3 + 0] = fminf(fmaxf(xv0 + d0 * 0.1f, 0.f), 1.f);
    ox[n*3 + 1] = fminf(fmaxf(xv1 + d1 * 0.1f, 0.f), 1.f);
    ox[n*3 + 2] = fminf(fmaxf(xv2 + d2 * 0.1f, 0.f), 1.f);
}

extern "C" void kernel_launch(void* const* d_in, const int* in_sizes, int n_in,
                              void* d_out, int out_size, void* d_ws, size_t ws_size,
                              hipStream_t stream) {
    const float* pos = (const float*)d_in[0];
    const float* x   = (const float*)d_in[1];
    const int*   c0  = (const int*)  d_in[2];
    const int*   c1  = (const int*)  d_in[3];
    const float* r   = (const float*)d_in[4];
    const float* rk  = (const float*)d_in[5];
    const float* b   = (const float*)d_in[6];
    const float* w   = (const float*)d_in[7];
    const float* h   = (const float*)d_in[8];
    const float* m   = (const float*)d_in[9];
    const float* s   = (const float*)d_in[10];
    float* out = (float*)d_out;
    float* ws  = (float*)d_ws;

    lenia_prep<<<NRULES + NCELLS/256, 256, 0, stream>>>(x, r, rk, b, w, ws);
    lenia_conv<<<CONV_BLOCKS, 256, 0, stream>>>(c0, ws);
    lenia_update<<<NCELLS/64, 64, 0, stream>>>(pos, x, c0, c1, h, m, s, ws, out);
}